// Round 1
// baseline (5263.259 us; speedup 1.0000x reference)
//
#include <hip/hip_runtime.h>

// ---------------- sizes ----------------
#define DD    256
#define LXX   256
#define NNEGN 8192

// ---------------- workspace offsets (floats) ----------------
#define OFF_GF   0
#define OFF_GB   (OFF_GF + 256*1024)
#define OFF_HF   (OFF_GB + 256*1024)
#define OFF_HB   (OFF_HF + 65536)
#define OFF_R1   (OFF_HB + 65536)
#define OFF_R3   (OFF_R1 + 65536)
#define OFF_MU   (OFF_R3 + 65536)
#define OFF_SGP  (OFF_MU + 65536)
#define OFF_Z    (OFF_SGP + 65536)
#define OFF_DENX (OFF_Z + 65536)
#define OFF_DENY (OFF_DENX + 256)
#define OFF_NUMX (OFF_DENY + 256)
#define OFF_ACC  (OFF_NUMX + 256)   // acc[0]=KL, acc[1]=log_xi, acc[2]=log_yi

__device__ __forceinline__ float sigf(float x) { return 1.f / (1.f + __expf(-x)); }

// =====================================================================
// Generic tiled GEMM: C[M,N] = act(A[M,K] @ B[N,K]^T + bias + bias2)
// A rows optionally gathered via idxA; optionally A+=A2 (HS=Hf+Hb).
// B rows optionally gathered via idxB.
// EPI 0: store C.  EPI 1: denOut[row] += sum_j exp(val).
// EPI 2: accOut += scale * sum exp(v)/(exp(v)+denIn[row]).
// Block 256 threads, tile 64x64, BK=32. All dims divide exactly here.
// =====================================================================
template<int ACT, int EPI>
__global__ __launch_bounds__(256) void gemm_bt(
    const float* __restrict__ A, const float* __restrict__ A2,
    const float* __restrict__ B,
    const int* __restrict__ idxA, const int* __restrict__ idxB,
    const float* __restrict__ bias, const float* __restrict__ bias2,
    float* __restrict__ C,
    float* __restrict__ denOut, const float* __restrict__ denIn,
    float* __restrict__ accOut, float scale,
    int M, int N, int K)
{
    __shared__ float As[32][65];
    __shared__ float Bs[32][65];
    __shared__ float red[256];

    const int tid = threadIdx.x;
    const int tx = tid & 15, ty = tid >> 4;
    const int m0 = blockIdx.y * 64, n0 = blockIdx.x * 64;
    const int lr = tid & 63;
    const int lk = (tid >> 6) * 8;

    const int ar = m0 + lr;
    const int arow = idxA ? idxA[ar] : ar;
    const float* Ap  = A + (size_t)arow * K;
    const float* A2p = A2 ? (A2 + (size_t)ar * K) : nullptr;
    const int brow = idxB ? idxB[n0 + lr] : (n0 + lr);
    const float* Bp = B + (size_t)brow * K;

    float acc[4][4];
#pragma unroll
    for (int i = 0; i < 4; ++i)
#pragma unroll
        for (int j = 0; j < 4; ++j) acc[i][j] = 0.f;

    for (int k0 = 0; k0 < K; k0 += 32) {
        float4 a0 = *(const float4*)(Ap + k0 + lk);
        float4 a1 = *(const float4*)(Ap + k0 + lk + 4);
        if (A2p) {
            float4 e0 = *(const float4*)(A2p + k0 + lk);
            float4 e1 = *(const float4*)(A2p + k0 + lk + 4);
            a0.x += e0.x; a0.y += e0.y; a0.z += e0.z; a0.w += e0.w;
            a1.x += e1.x; a1.y += e1.y; a1.z += e1.z; a1.w += e1.w;
        }
        float4 b0 = *(const float4*)(Bp + k0 + lk);
        float4 b1 = *(const float4*)(Bp + k0 + lk + 4);

        As[lk+0][lr] = a0.x; As[lk+1][lr] = a0.y; As[lk+2][lr] = a0.z; As[lk+3][lr] = a0.w;
        As[lk+4][lr] = a1.x; As[lk+5][lr] = a1.y; As[lk+6][lr] = a1.z; As[lk+7][lr] = a1.w;
        Bs[lk+0][lr] = b0.x; Bs[lk+1][lr] = b0.y; Bs[lk+2][lr] = b0.z; Bs[lk+3][lr] = b0.w;
        Bs[lk+4][lr] = b1.x; Bs[lk+5][lr] = b1.y; Bs[lk+6][lr] = b1.z; Bs[lk+7][lr] = b1.w;
        __syncthreads();

#pragma unroll
        for (int kk = 0; kk < 32; ++kk) {
            float av[4], bv[4];
#pragma unroll
            for (int i = 0; i < 4; ++i) av[i] = As[kk][ty*4 + i];
#pragma unroll
            for (int j = 0; j < 4; ++j) bv[j] = Bs[kk][tx*4 + j];
#pragma unroll
            for (int i = 0; i < 4; ++i)
#pragma unroll
                for (int j = 0; j < 4; ++j)
                    acc[i][j] = fmaf(av[i], bv[j], acc[i][j]);
        }
        __syncthreads();
    }

    if (EPI == 0) {
#pragma unroll
        for (int i = 0; i < 4; ++i) {
            int r = m0 + ty*4 + i;
#pragma unroll
            for (int j = 0; j < 4; ++j) {
                int cc = n0 + tx*4 + j;
                float v = acc[i][j];
                if (bias)  v += bias[cc];
                if (bias2) v += bias2[cc];
                if (ACT == 1) v = v > 0.f ? v : 0.f;
                C[(size_t)r * N + cc] = v;
            }
        }
    } else if (EPI == 1) {
#pragma unroll
        for (int i = 0; i < 4; ++i) {
            float rs = 0.f;
#pragma unroll
            for (int j = 0; j < 4; ++j) rs += __expf(acc[i][j]);
            rs += __shfl_xor(rs, 1, 64);
            rs += __shfl_xor(rs, 2, 64);
            rs += __shfl_xor(rs, 4, 64);
            rs += __shfl_xor(rs, 8, 64);
            if (tx == 0) atomicAdd(&denOut[m0 + ty*4 + i], rs);
        }
    } else {   // EPI == 2
        float tsum = 0.f;
#pragma unroll
        for (int i = 0; i < 4; ++i) {
            int r = m0 + ty*4 + i;
            float dn = denIn[r];
#pragma unroll
            for (int j = 0; j < 4; ++j) {
                float e = __expf(acc[i][j]);
                tsum += e / (e + dn);
            }
        }
        red[tid] = tsum;
        __syncthreads();
        for (int off = 128; off > 0; off >>= 1) {
            if (tid < off) red[tid] += red[tid + off];
            __syncthreads();
        }
        if (tid == 0) atomicAdd(accOut, red[0] * scale);
    }
}

// =====================================================================
// Sequential LSTM scan. One block per direction (2 blocks total),
// 1024 threads. Thread (oo = tid>>3, s = tid&7) owns 8 output rows
// o_r = oo + 128*r with the k-slice {4s + 32j + 0..3 : j=0..7}.
// Whh rows live in 256 VGPRs/thread; h broadcast via LDS float4 with
// 8 MACs per loaded float; slice partials combined via shfl_xor(1,2,4).
// =====================================================================
__global__ __launch_bounds__(1024, 4) void scan_kernel(
    const float* __restrict__ Gf, const float* __restrict__ Gb,
    const float* __restrict__ Wf, const float* __restrict__ Wb,
    const float* __restrict__ h0, const float* __restrict__ c0,
    float* __restrict__ Hf, float* __restrict__ Hb)
{
    const int dir = blockIdx.x;
    const float* G = dir ? Gb : Gf;
    const float* W = dir ? Wb : Wf;
    float* H = dir ? Hb : Hf;

    const int tid = threadIdx.x;
    const int oo = tid >> 3;
    const int s  = tid & 7;

    __shared__ float4 h4[64];
    __shared__ float  gate[1024];

    // load Whh slices into registers (8 rows x 8 float4 = 256 VGPRs)
    float4 w4[8][8];
#pragma unroll
    for (int r = 0; r < 8; ++r) {
        const float* wr = W + (size_t)(oo + 128*r) * 256 + s*4;
#pragma unroll
        for (int j = 0; j < 8; ++j)
            w4[r][j] = *(const float4*)(wr + 32*j);
    }

    float c = 0.f;
    if (tid < 256) {
        ((float*)h4)[tid] = h0[dir*256 + tid];
        c = c0[dir*256 + tid];
    }
    __syncthreads();

    for (int t = 0; t < 256; ++t) {
        float acc[8];
#pragma unroll
        for (int r = 0; r < 8; ++r) acc[r] = 0.f;
#pragma unroll
        for (int j = 0; j < 8; ++j) {
            float4 hv = h4[s + 8*j];
#pragma unroll
            for (int r = 0; r < 8; ++r) {
                acc[r] = fmaf(w4[r][j].x, hv.x, acc[r]);
                acc[r] = fmaf(w4[r][j].y, hv.y, acc[r]);
                acc[r] = fmaf(w4[r][j].z, hv.z, acc[r]);
                acc[r] = fmaf(w4[r][j].w, hv.w, acc[r]);
            }
        }
#pragma unroll
        for (int r = 0; r < 8; ++r) {
            acc[r] += __shfl_xor(acc[r], 1, 64);
            acc[r] += __shfl_xor(acc[r], 2, 64);
            acc[r] += __shfl_xor(acc[r], 4, 64);
        }
        if (s == 0) {
#pragma unroll
            for (int r = 0; r < 8; ++r)
                gate[oo + 128*r] = acc[r] + G[t*1024 + oo + 128*r];
        }
        __syncthreads();
        if (tid < 256) {
            float gi = gate[tid];
            float gf = gate[256 + tid];
            float gg = gate[512 + tid];
            float go = gate[768 + tid];
            c = sigf(gf) * c + sigf(gi) * tanhf(gg);
            float h = sigf(go) * tanhf(c);
            H[t*256 + tid] = h;
            ((float*)h4)[tid] = h;
        }
        __syncthreads();
    }
}

// z = mu + eps*softplus(sgp); KL partial sums -> acc[0]
__global__ __launch_bounds__(256) void zkl_kernel(
    const float* __restrict__ MU, const float* __restrict__ SGP,
    const float* __restrict__ eps, float* __restrict__ Z,
    float* __restrict__ acc)
{
    int idx = blockIdx.x * 256 + threadIdx.x;
    float mu = MU[idx], sp = SGP[idx];
    float sg = (sp > 15.f) ? sp : log1pf(__expf(sp));
    float z = fmaf(eps[idx], sg, mu);
    Z[idx] = z;
    float kle = -logf(sg) + 0.5f * (sg*sg + mu*mu) - 0.5f;
#pragma unroll
    for (int m = 1; m < 64; m <<= 1) kle += __shfl_xor(kle, m, 64);
    __shared__ float wsum[4];
    int lane = threadIdx.x & 63, wv = threadIdx.x >> 6;
    if (lane == 0) wsum[wv] = kle;
    __syncthreads();
    if (threadIdx.x == 0) atomicAdd(acc + 0, wsum[0] + wsum[1] + wsum[2] + wsum[3]);
}

// num_x[i] = exp(dot(z_i, Ax[x_i]))
__global__ void numx_kernel(const float* __restrict__ Z, const float* __restrict__ Ax,
                            const int* __restrict__ x, float* __restrict__ numx)
{
    int i = blockIdx.x, lane = threadIdx.x;
    const float4* z4 = (const float4*)(Z + (size_t)i * 256);
    const float4* a4 = (const float4*)(Ax + (size_t)x[i] * 256);
    float4 zv = z4[lane], av = a4[lane];
    float sdot = zv.x*av.x + zv.y*av.y + zv.z*av.z + zv.w*av.w;
#pragma unroll
    for (int m = 1; m < 64; m <<= 1) sdot += __shfl_xor(sdot, m, 64);
    if (lane == 0) numx[i] = __expf(sdot);
}

// acc[1] = sum_i numx/(numx+denx)
__global__ __launch_bounds__(256) void logxi_kernel(
    const float* __restrict__ numx, const float* __restrict__ denx,
    float* __restrict__ acc)
{
    int tid = threadIdx.x;
    float nx = numx[tid];
    float v = nx / (nx + denx[tid]);
#pragma unroll
    for (int m = 1; m < 64; m <<= 1) v += __shfl_xor(v, m, 64);
    __shared__ float wsum[4];
    if ((tid & 63) == 0) wsum[tid >> 6] = v;
    __syncthreads();
    if (tid == 0) acc[1] = wsum[0] + wsum[1] + wsum[2] + wsum[3];
}

__global__ void final_kernel(const float* __restrict__ acc, float* __restrict__ out)
{
    out[0] = -(acc[1] + acc[2] - acc[0]);
}

// =====================================================================
extern "C" void kernel_launch(void* const* d_in, const int* in_sizes, int n_in,
                              void* d_out, int out_size, void* d_ws, size_t ws_size,
                              hipStream_t stream)
{
    const int*   x     = (const int*)d_in[0];
    const int*   y     = (const int*)d_in[1];
    const int*   neg_x = (const int*)d_in[2];
    const int*   neg_y = (const int*)d_in[3];
    const float* eps   = (const float*)d_in[4];
    const float* h0    = (const float*)d_in[5];
    const float* c0    = (const float*)d_in[6];
    const float* E_x   = (const float*)d_in[7];
    const float* Wih_f = (const float*)d_in[8];
    const float* Whh_f = (const float*)d_in[9];
    const float* bih_f = (const float*)d_in[10];
    const float* bhh_f = (const float*)d_in[11];
    const float* Wih_b = (const float*)d_in[12];
    const float* Whh_b = (const float*)d_in[13];
    const float* bih_b = (const float*)d_in[14];
    const float* bhh_b = (const float*)d_in[15];
    const float* Wmu1  = (const float*)d_in[16];
    const float* bmu1  = (const float*)d_in[17];
    const float* Wmu2  = (const float*)d_in[18];
    const float* bmu2  = (const float*)d_in[19];
    const float* Wsg1  = (const float*)d_in[20];
    const float* bsg1  = (const float*)d_in[21];
    const float* Wsg2  = (const float*)d_in[22];
    const float* bsg2  = (const float*)d_in[23];
    const float* Ax    = (const float*)d_in[24];
    const float* Ay    = (const float*)d_in[25];

    float* ws   = (float*)d_ws;
    float* GF   = ws + OFF_GF;
    float* GB   = ws + OFF_GB;
    float* HF   = ws + OFF_HF;
    float* HB   = ws + OFF_HB;
    float* R1   = ws + OFF_R1;
    float* R3   = ws + OFF_R3;
    float* MU   = ws + OFF_MU;
    float* SGP  = ws + OFF_SGP;
    float* Z    = ws + OFF_Z;
    float* DENX = ws + OFF_DENX;
    float* DENY = ws + OFF_DENY;
    float* NUMX = ws + OFF_NUMX;
    float* ACC  = ws + OFF_ACC;

    // zero den/num/acc (re-zeroed every call: graph replays re-run this)
    hipMemsetAsync(DENX, 0, (3*256 + 4) * sizeof(float), stream);

    // gate precompute: Gpre = E_x[x] @ Wih^T + bih + bhh   [256,1024]
    gemm_bt<0,0><<<dim3(16,4), 256, 0, stream>>>(
        E_x, nullptr, Wih_f, x, nullptr, bih_f, bhh_f, GF,
        nullptr, nullptr, nullptr, 0.f, 256, 1024, 256);
    gemm_bt<0,0><<<dim3(16,4), 256, 0, stream>>>(
        E_x, nullptr, Wih_b, x, nullptr, bih_b, bhh_b, GB,
        nullptr, nullptr, nullptr, 0.f, 256, 1024, 256);

    // sequential LSTM (2 independent direction chains)
    scan_kernel<<<2, 1024, 0, stream>>>(GF, GB, Whh_f, Whh_b, h0, c0, HF, HB);

    // heads: R = relu((Hf+Hb) @ W1^T + b1); out = R @ W2^T + b2
    gemm_bt<1,0><<<dim3(4,4), 256, 0, stream>>>(
        HF, HB, Wmu1, nullptr, nullptr, bmu1, nullptr, R1,
        nullptr, nullptr, nullptr, 0.f, 256, 256, 256);
    gemm_bt<1,0><<<dim3(4,4), 256, 0, stream>>>(
        HF, HB, Wsg1, nullptr, nullptr, bsg1, nullptr, R3,
        nullptr, nullptr, nullptr, 0.f, 256, 256, 256);
    gemm_bt<0,0><<<dim3(4,4), 256, 0, stream>>>(
        R1, nullptr, Wmu2, nullptr, nullptr, bmu2, nullptr, MU,
        nullptr, nullptr, nullptr, 0.f, 256, 256, 256);
    gemm_bt<0,0><<<dim3(4,4), 256, 0, stream>>>(
        R3, nullptr, Wsg2, nullptr, nullptr, bsg2, nullptr, SGP,
        nullptr, nullptr, nullptr, 0.f, 256, 256, 256);

    // z, KL
    zkl_kernel<<<256, 256, 0, stream>>>(MU, SGP, eps, Z, ACC);

    // den_x[i] = sum_n exp(z_i . Ax[neg_x[n]]), fused exp+rowsum epilogue
    gemm_bt<0,1><<<dim3(128,4), 256, 0, stream>>>(
        Z, nullptr, Ax, nullptr, neg_x, nullptr, nullptr, nullptr,
        DENX, nullptr, nullptr, 0.f, 256, 8192, 256);
    gemm_bt<0,1><<<dim3(128,4), 256, 0, stream>>>(
        Z, nullptr, Ay, nullptr, neg_y, nullptr, nullptr, nullptr,
        DENY, nullptr, nullptr, 0.f, 256, 8192, 256);

    // x-term
    numx_kernel<<<256, 64, 0, stream>>>(Z, Ax, x, NUMX);
    logxi_kernel<<<1, 256, 0, stream>>>(NUMX, DENX, ACC);

    // y-term: ratio-sum epilogue, scaled by 1/Lx
    gemm_bt<0,2><<<dim3(4,4), 256, 0, stream>>>(
        Z, nullptr, Ay, nullptr, y, nullptr, nullptr, nullptr,
        nullptr, DENY, ACC + 2, 1.f/256.f, 256, 256, 256);

    final_kernel<<<1, 1, 0, stream>>>(ACC, (float*)d_out);
}

// Round 2
// 1152.204 us; speedup vs baseline: 4.5680x; 4.5680x over previous
//
#include <hip/hip_runtime.h>

// ---------------- sizes ----------------
#define DD    256
#define LXX   256
#define NNEGN 8192
#define NBLK  16     // scan blocks: 8 per direction

// ---------------- workspace offsets (floats) ----------------
#define OFF_GF   0
#define OFF_GB   (OFF_GF + 256*1024)
#define OFF_HF   (OFF_GB + 256*1024)
#define OFF_HB   (OFF_HF + 65536)
#define OFF_R1   (OFF_HB + 65536)
#define OFF_R3   (OFF_R1 + 65536)
#define OFF_MU   (OFF_R3 + 65536)
#define OFF_SGP  (OFF_MU + 65536)
#define OFF_Z    (OFF_SGP + 65536)
#define OFF_DENX (OFF_Z + 65536)
#define OFF_DENY (OFF_DENX + 256)
#define OFF_NUMX (OFF_DENY + 256)
#define OFF_ACC  (OFF_NUMX + 256)   // acc[0]=KL, acc[1]=log_xi, acc[2]=log_yi
#define OFF_CNT  (OFF_ACC + 4)      // scan barrier counter (int)
#define OFF_HCUR (OFF_CNT + 4)      // current h, [2][256]

__device__ __forceinline__ float sigf(float x) { return 1.f / (1.f + __expf(-x)); }

// =====================================================================
// Generic tiled GEMM: C[M,N] = act(A[M,K] @ B[N,K]^T + bias + bias2)
// (unchanged from round 1 — passed)
// =====================================================================
template<int ACT, int EPI>
__global__ __launch_bounds__(256) void gemm_bt(
    const float* __restrict__ A, const float* __restrict__ A2,
    const float* __restrict__ B,
    const int* __restrict__ idxA, const int* __restrict__ idxB,
    const float* __restrict__ bias, const float* __restrict__ bias2,
    float* __restrict__ C,
    float* __restrict__ denOut, const float* __restrict__ denIn,
    float* __restrict__ accOut, float scale,
    int M, int N, int K)
{
    __shared__ float As[32][65];
    __shared__ float Bs[32][65];
    __shared__ float red[256];

    const int tid = threadIdx.x;
    const int tx = tid & 15, ty = tid >> 4;
    const int m0 = blockIdx.y * 64, n0 = blockIdx.x * 64;
    const int lr = tid & 63;
    const int lk = (tid >> 6) * 8;

    const int ar = m0 + lr;
    const int arow = idxA ? idxA[ar] : ar;
    const float* Ap  = A + (size_t)arow * K;
    const float* A2p = A2 ? (A2 + (size_t)ar * K) : nullptr;
    const int brow = idxB ? idxB[n0 + lr] : (n0 + lr);
    const float* Bp = B + (size_t)brow * K;

    float acc[4][4];
#pragma unroll
    for (int i = 0; i < 4; ++i)
#pragma unroll
        for (int j = 0; j < 4; ++j) acc[i][j] = 0.f;

    for (int k0 = 0; k0 < K; k0 += 32) {
        float4 a0 = *(const float4*)(Ap + k0 + lk);
        float4 a1 = *(const float4*)(Ap + k0 + lk + 4);
        if (A2p) {
            float4 e0 = *(const float4*)(A2p + k0 + lk);
            float4 e1 = *(const float4*)(A2p + k0 + lk + 4);
            a0.x += e0.x; a0.y += e0.y; a0.z += e0.z; a0.w += e0.w;
            a1.x += e1.x; a1.y += e1.y; a1.z += e1.z; a1.w += e1.w;
        }
        float4 b0 = *(const float4*)(Bp + k0 + lk);
        float4 b1 = *(const float4*)(Bp + k0 + lk + 4);

        As[lk+0][lr] = a0.x; As[lk+1][lr] = a0.y; As[lk+2][lr] = a0.z; As[lk+3][lr] = a0.w;
        As[lk+4][lr] = a1.x; As[lk+5][lr] = a1.y; As[lk+6][lr] = a1.z; As[lk+7][lr] = a1.w;
        Bs[lk+0][lr] = b0.x; Bs[lk+1][lr] = b0.y; Bs[lk+2][lr] = b0.z; Bs[lk+3][lr] = b0.w;
        Bs[lk+4][lr] = b1.x; Bs[lk+5][lr] = b1.y; Bs[lk+6][lr] = b1.z; Bs[lk+7][lr] = b1.w;
        __syncthreads();

#pragma unroll
        for (int kk = 0; kk < 32; ++kk) {
            float av[4], bv[4];
#pragma unroll
            for (int i = 0; i < 4; ++i) av[i] = As[kk][ty*4 + i];
#pragma unroll
            for (int j = 0; j < 4; ++j) bv[j] = Bs[kk][tx*4 + j];
#pragma unroll
            for (int i = 0; i < 4; ++i)
#pragma unroll
                for (int j = 0; j < 4; ++j)
                    acc[i][j] = fmaf(av[i], bv[j], acc[i][j]);
        }
        __syncthreads();
    }

    if (EPI == 0) {
#pragma unroll
        for (int i = 0; i < 4; ++i) {
            int r = m0 + ty*4 + i;
#pragma unroll
            for (int j = 0; j < 4; ++j) {
                int cc = n0 + tx*4 + j;
                float v = acc[i][j];
                if (bias)  v += bias[cc];
                if (bias2) v += bias2[cc];
                if (ACT == 1) v = v > 0.f ? v : 0.f;
                C[(size_t)r * N + cc] = v;
            }
        }
    } else if (EPI == 1) {
#pragma unroll
        for (int i = 0; i < 4; ++i) {
            float rs = 0.f;
#pragma unroll
            for (int j = 0; j < 4; ++j) rs += __expf(acc[i][j]);
            rs += __shfl_xor(rs, 1, 64);
            rs += __shfl_xor(rs, 2, 64);
            rs += __shfl_xor(rs, 4, 64);
            rs += __shfl_xor(rs, 8, 64);
            if (tx == 0) atomicAdd(&denOut[m0 + ty*4 + i], rs);
        }
    } else {   // EPI == 2
        float tsum = 0.f;
#pragma unroll
        for (int i = 0; i < 4; ++i) {
            int r = m0 + ty*4 + i;
            float dn = denIn[r];
#pragma unroll
            for (int j = 0; j < 4; ++j) {
                float e = __expf(acc[i][j]);
                tsum += e / (e + dn);
            }
        }
        red[tid] = tsum;
        __syncthreads();
        for (int off = 128; off > 0; off >>= 1) {
            if (tid < off) red[tid] += red[tid + off];
            __syncthreads();
        }
        if (tid == 0) atomicAdd(accOut, red[0] * scale);
    }
}

// =====================================================================
// Multi-block LSTM scan. 16 blocks (8 per direction) x 512 threads.
// Block owns 32 hidden units u in [u0, u0+32) and the 128 gate rows
// {g*256+u}. Thread (ri = tid>>2, s = tid&3) owns ONE gate row with a
// 64-wide k-slice -> 16 float4 of Whh in VGPRs (64 regs, no spill).
// c is thread-local in the 32 updater threads. Only h (256 floats per
// direction) crosses blocks each step, via release-fence + monotonic
// atomic counter + acquire-fence (device scope, L1-invalidating).
// =====================================================================
__global__ __launch_bounds__(512) void scan_mb_kernel(
    const float* __restrict__ Gf, const float* __restrict__ Gb,
    const float* __restrict__ Wf, const float* __restrict__ Wb,
    const float* __restrict__ h0, const float* __restrict__ c0,
    float* __restrict__ Hf, float* __restrict__ Hb,
    float* __restrict__ Hcur, int* __restrict__ cnt)
{
    const int dir = blockIdx.x >> 3;
    const int u0  = (blockIdx.x & 7) * 32;
    const float* G = dir ? Gb : Gf;
    const float* W = dir ? Wb : Wf;
    float* H  = dir ? Hb : Hf;
    float* hc = Hcur + dir * 256;

    const int tid = threadIdx.x;
    const int ri  = tid >> 2;      // 0..127: which of my block's gate rows
    const int s   = tid & 3;       // k-slice
    const int g   = ri >> 5;       // gate index 0..3 (i,f,g,o)
    const int ul  = ri & 31;       // local unit
    const int row = g * 256 + u0 + ul;

    // 64 weights/thread, register-resident
    float4 w4[16];
    {
        const float4* wr = (const float4*)(W + (size_t)row * 256 + s * 64);
#pragma unroll
        for (int j = 0; j < 16; ++j) w4[j] = wr[j];
    }

    float c = (tid < 32) ? c0[dir * 256 + u0 + tid] : 0.f;

    __shared__ float4 h4[64];
    __shared__ float  gate[128];

    for (int t = 0; t < 256; ++t) {
        // stage h_t into LDS (t=0: from input h0; else from global Hcur)
        if (tid < 64) {
            const float4* src = (const float4*)((t == 0) ? (h0 + dir * 256) : hc);
            h4[tid] = src[tid];
        }
        __syncthreads();

        // my row's partial dot over k-slice [64s, 64s+64)
        float acc = 0.f;
#pragma unroll
        for (int j = 0; j < 16; ++j) {
            float4 hv = h4[s * 16 + j];
            acc = fmaf(w4[j].x, hv.x, acc);
            acc = fmaf(w4[j].y, hv.y, acc);
            acc = fmaf(w4[j].z, hv.z, acc);
            acc = fmaf(w4[j].w, hv.w, acc);
        }
        // combine the 4 k-slices (lanes 4k..4k+3 of the same wave)
        acc += __shfl_xor(acc, 1, 64);
        acc += __shfl_xor(acc, 2, 64);
        if (s == 0) gate[ri] = acc;
        __syncthreads();

        // h/c update for this block's 32 units
        if (tid < 32) {
            const int u = u0 + tid;
            const float* Gt = G + (size_t)t * 1024;
            float gi = gate[tid]       + Gt[u];
            float gf = gate[32 + tid]  + Gt[256 + u];
            float gg = gate[64 + tid]  + Gt[512 + u];
            float go = gate[96 + tid]  + Gt[768 + u];
            c = sigf(gf) * c + sigf(gi) * tanhf(gg);
            float h = sigf(go) * tanhf(c);
            H[t * 256 + u] = h;   // fp32 record for the heads
            hc[u] = h;            // cross-block h
            __threadfence();      // release: push h beyond XCD L2
        }
        __syncthreads();

        // one device-scope barrier per step (monotonic counter)
        if (tid == 0) {
            atomicAdd(cnt, 1);
            const int target = (t + 1) * NBLK;
            while (__hip_atomic_load(cnt, __ATOMIC_RELAXED, __HIP_MEMORY_SCOPE_AGENT) < target) {
                __builtin_amdgcn_s_sleep(2);
            }
            __threadfence();      // acquire: invalidate L1 before reading h
        }
        __syncthreads();
    }
}

// z = mu + eps*softplus(sgp); KL partial sums -> acc[0]
__global__ __launch_bounds__(256) void zkl_kernel(
    const float* __restrict__ MU, const float* __restrict__ SGP,
    const float* __restrict__ eps, float* __restrict__ Z,
    float* __restrict__ acc)
{
    int idx = blockIdx.x * 256 + threadIdx.x;
    float mu = MU[idx], sp = SGP[idx];
    float sg = (sp > 15.f) ? sp : log1pf(__expf(sp));
    float z = fmaf(eps[idx], sg, mu);
    Z[idx] = z;
    float kle = -logf(sg) + 0.5f * (sg*sg + mu*mu) - 0.5f;
#pragma unroll
    for (int m = 1; m < 64; m <<= 1) kle += __shfl_xor(kle, m, 64);
    __shared__ float wsum[4];
    int lane = threadIdx.x & 63, wv = threadIdx.x >> 6;
    if (lane == 0) wsum[wv] = kle;
    __syncthreads();
    if (threadIdx.x == 0) atomicAdd(acc + 0, wsum[0] + wsum[1] + wsum[2] + wsum[3]);
}

// num_x[i] = exp(dot(z_i, Ax[x_i]))
__global__ void numx_kernel(const float* __restrict__ Z, const float* __restrict__ Ax,
                            const int* __restrict__ x, float* __restrict__ numx)
{
    int i = blockIdx.x, lane = threadIdx.x;
    const float4* z4 = (const float4*)(Z + (size_t)i * 256);
    const float4* a4 = (const float4*)(Ax + (size_t)x[i] * 256);
    float4 zv = z4[lane], av = a4[lane];
    float sdot = zv.x*av.x + zv.y*av.y + zv.z*av.z + zv.w*av.w;
#pragma unroll
    for (int m = 1; m < 64; m <<= 1) sdot += __shfl_xor(sdot, m, 64);
    if (lane == 0) numx[i] = __expf(sdot);
}

// acc[1] = sum_i numx/(numx+denx)
__global__ __launch_bounds__(256) void logxi_kernel(
    const float* __restrict__ numx, const float* __restrict__ denx,
    float* __restrict__ acc)
{
    int tid = threadIdx.x;
    float nx = numx[tid];
    float v = nx / (nx + denx[tid]);
#pragma unroll
    for (int m = 1; m < 64; m <<= 1) v += __shfl_xor(v, m, 64);
    __shared__ float wsum[4];
    if ((tid & 63) == 0) wsum[tid >> 6] = v;
    __syncthreads();
    if (tid == 0) acc[1] = wsum[0] + wsum[1] + wsum[2] + wsum[3];
}

__global__ void final_kernel(const float* __restrict__ acc, float* __restrict__ out)
{
    out[0] = -(acc[1] + acc[2] - acc[0]);
}

// =====================================================================
extern "C" void kernel_launch(void* const* d_in, const int* in_sizes, int n_in,
                              void* d_out, int out_size, void* d_ws, size_t ws_size,
                              hipStream_t stream)
{
    const int*   x     = (const int*)d_in[0];
    const int*   y     = (const int*)d_in[1];
    const int*   neg_x = (const int*)d_in[2];
    const int*   neg_y = (const int*)d_in[3];
    const float* eps   = (const float*)d_in[4];
    const float* h0    = (const float*)d_in[5];
    const float* c0    = (const float*)d_in[6];
    const float* E_x   = (const float*)d_in[7];
    const float* Wih_f = (const float*)d_in[8];
    const float* Whh_f = (const float*)d_in[9];
    const float* bih_f = (const float*)d_in[10];
    const float* bhh_f = (const float*)d_in[11];
    const float* Wih_b = (const float*)d_in[12];
    const float* Whh_b = (const float*)d_in[13];
    const float* bih_b = (const float*)d_in[14];
    const float* bhh_b = (const float*)d_in[15];
    const float* Wmu1  = (const float*)d_in[16];
    const float* bmu1  = (const float*)d_in[17];
    const float* Wmu2  = (const float*)d_in[18];
    const float* bmu2  = (const float*)d_in[19];
    const float* Wsg1  = (const float*)d_in[20];
    const float* bsg1  = (const float*)d_in[21];
    const float* Wsg2  = (const float*)d_in[22];
    const float* bsg2  = (const float*)d_in[23];
    const float* Ax    = (const float*)d_in[24];
    const float* Ay    = (const float*)d_in[25];

    float* ws   = (float*)d_ws;
    float* GF   = ws + OFF_GF;
    float* GB   = ws + OFF_GB;
    float* HF   = ws + OFF_HF;
    float* HB   = ws + OFF_HB;
    float* R1   = ws + OFF_R1;
    float* R3   = ws + OFF_R3;
    float* MU   = ws + OFF_MU;
    float* SGP  = ws + OFF_SGP;
    float* Z    = ws + OFF_Z;
    float* DENX = ws + OFF_DENX;
    float* DENY = ws + OFF_DENY;
    float* NUMX = ws + OFF_NUMX;
    float* ACC  = ws + OFF_ACC;
    int*   CNT  = (int*)(ws + OFF_CNT);
    float* HCUR = ws + OFF_HCUR;

    // zero den/num/acc + barrier counter (runs inside the graph each replay)
    hipMemsetAsync(DENX, 0, (3*256 + 8) * sizeof(float), stream);

    // gate precompute: Gpre = E_x[x] @ Wih^T + bih + bhh   [256,1024]
    gemm_bt<0,0><<<dim3(16,4), 256, 0, stream>>>(
        E_x, nullptr, Wih_f, x, nullptr, bih_f, bhh_f, GF,
        nullptr, nullptr, nullptr, 0.f, 256, 1024, 256);
    gemm_bt<0,0><<<dim3(16,4), 256, 0, stream>>>(
        E_x, nullptr, Wih_b, x, nullptr, bih_b, bhh_b, GB,
        nullptr, nullptr, nullptr, 0.f, 256, 1024, 256);

    // sequential LSTM: 16 blocks, register-resident weights
    scan_mb_kernel<<<NBLK, 512, 0, stream>>>(
        GF, GB, Whh_f, Whh_b, h0, c0, HF, HB, HCUR, CNT);

    // heads: R = relu((Hf+Hb) @ W1^T + b1); out = R @ W2^T + b2
    gemm_bt<1,0><<<dim3(4,4), 256, 0, stream>>>(
        HF, HB, Wmu1, nullptr, nullptr, bmu1, nullptr, R1,
        nullptr, nullptr, nullptr, 0.f, 256, 256, 256);
    gemm_bt<1,0><<<dim3(4,4), 256, 0, stream>>>(
        HF, HB, Wsg1, nullptr, nullptr, bsg1, nullptr, R3,
        nullptr, nullptr, nullptr, 0.f, 256, 256, 256);
    gemm_bt<0,0><<<dim3(4,4), 256, 0, stream>>>(
        R1, nullptr, Wmu2, nullptr, nullptr, bmu2, nullptr, MU,
        nullptr, nullptr, nullptr, 0.f, 256, 256, 256);
    gemm_bt<0,0><<<dim3(4,4), 256, 0, stream>>>(
        R3, nullptr, Wsg2, nullptr, nullptr, bsg2, nullptr, SGP,
        nullptr, nullptr, nullptr, 0.f, 256, 256, 256);

    // z, KL
    zkl_kernel<<<256, 256, 0, stream>>>(MU, SGP, eps, Z, ACC);

    // den_x[i] = sum_n exp(z_i . A[neg[n]]), fused exp+rowsum epilogue
    gemm_bt<0,1><<<dim3(128,4), 256, 0, stream>>>(
        Z, nullptr, Ax, nullptr, neg_x, nullptr, nullptr, nullptr,
        DENX, nullptr, nullptr, 0.f, 256, 8192, 256);
    gemm_bt<0,1><<<dim3(128,4), 256, 0, stream>>>(
        Z, nullptr, Ay, nullptr, neg_y, nullptr, nullptr, nullptr,
        DENY, nullptr, nullptr, 0.f, 256, 8192, 256);

    // x-term
    numx_kernel<<<256, 64, 0, stream>>>(Z, Ax, x, NUMX);
    logxi_kernel<<<1, 256, 0, stream>>>(NUMX, DENX, ACC);

    // y-term: ratio-sum epilogue, scaled by 1/Lx
    gemm_bt<0,2><<<dim3(4,4), 256, 0, stream>>>(
        Z, nullptr, Ay, nullptr, y, nullptr, nullptr, nullptr,
        nullptr, DENY, ACC + 2, 1.f/256.f, 256, 256, 256);

    final_kernel<<<1, 1, 0, stream>>>(ACC, (float*)d_out);
}